// Round 4
// baseline (952.190 us; speedup 1.0000x reference)
//
#include <hip/hip_runtime.h>

typedef __attribute__((ext_vector_type(8))) short short8;
typedef __attribute__((ext_vector_type(4))) short short4v;
typedef __attribute__((ext_vector_type(4))) float float4v;

#define MFMA16(a, b, c) __builtin_amdgcn_mfma_f32_16x16x32_bf16((a), (b), (c), 0, 0, 0)

constexpr int kThreads = 512;
// LDS (ushort units):
//   [0,     32768)  K  : elem(pos,d) swizzled, 4-d-runs contiguous (b64 frags)
//   [32768, 65536)  V  : elem(pos,d) swizzled, 4-pos-runs contiguous (b64 frags)
//   [65536, 77824)  Wq^T/Wk^T/Wv^T staging (3 x 4096), 8-d-runs (b128 frags)
//   [77824, 81920)  Wd^T : 4-d-runs (b64 frags)
constexpr int LDS_TOTAL_BYTES = 163840;  // 160 KiB -> 1 block/CU

static __device__ __forceinline__ unsigned short f2bf(float f) {
  // round-to-nearest-even fp32 -> bf16
  unsigned int u = __float_as_uint(f);
  u = (u + 0x7fffu + ((u >> 16) & 1u)) >> 16;
  return (unsigned short)u;
}
static __device__ __forceinline__ short8 cat4(short4v lo, short4v hi) {
  return __builtin_shufflevector(lo, hi, 0, 1, 2, 3, 4, 5, 6, 7);
}

// XOR-swizzled LDS index helpers (ushort units). Same function on write and
// read sides -> consistency by construction.
static __device__ __forceinline__ int ksw_idx(int pos, int d) {
  // value K[pos][d]; 4 consecutive d per lane (b64)
  return ((((d >> 2) << 11) + (pos << 2) + (d & 3)) ^ (((d >> 2) & 3) << 2));
}
static __device__ __forceinline__ int vsw_idx(int pos, int d) {
  // value V[pos][d]; 4 consecutive pos per lane (b64)
  return ((((pos >> 2) << 8) + (d << 2) + (pos & 3)) ^ (((pos >> 2) & 3) << 2));
}
static __device__ __forceinline__ int wsw_idx(int e, int d) {
  // value W[d][e] (= W^T[e][d]); 8 consecutive d per lane (b128)
  return ((((d >> 3) << 9) + (e << 3) + (d & 7)) ^ (((d >> 3) & 3) << 3));
}
static __device__ __forceinline__ int wdsw_idx(int e, int d) {
  // value Wd[d][e]; 4 consecutive d per lane (b64)
  return ((((d >> 2) << 8) + (e << 2) + (d & 3)) ^ (((d >> 2) & 3) << 2));
}

__global__ __launch_bounds__(kThreads, 2) void ts_attn_fused(
    const float* __restrict__ x, const float* __restrict__ Wq_t,
    const float* __restrict__ Wk_t, const float* __restrict__ Wv_t,
    const float* __restrict__ Wq_s, const float* __restrict__ Wk_s,
    const float* __restrict__ Wv_s, const float* __restrict__ Wd_t,
    const float* __restrict__ bd_t, const float* __restrict__ Wd_s,
    const float* __restrict__ bd_s, float* __restrict__ out,
    unsigned short* __restrict__ qws) {
  extern __shared__ __align__(16) unsigned short smem[];
  unsigned short* Ksw = smem;            // 32768 us
  unsigned short* Vsw = smem + 32768;    // 32768 us
  unsigned short* Wst = smem + 65536;    // 12288 us (3 x 4096)
  unsigned short* Wdsw = smem + 77824;   // 4096 us

  const int tid = threadIdx.x;
  const int wv = tid >> 6;
  const int lane = tid & 63;
  const int ln = lane & 15;   // q position within 16-tile
  const int quad = lane >> 4;
  const int b = blockIdx.x;

  const float* xb = x + (size_t)b * (512 * 64);
  float* outb = out + (size_t)b * (512 * 64);
  unsigned short* qg = qws + (size_t)b * (512 * 64);  // Q bf16, row-major [pos][e]

  // bias preload: epilogue lane covers channels e = nt*16 + quad*4 + r
  float4v bd4[4];
#pragma unroll
  for (int nt = 0; nt < 4; ++nt) {
    const float4v bt = *reinterpret_cast<const float4v*>(bd_t + nt * 16 + quad * 4);
    const float4v bs = *reinterpret_cast<const float4v*>(bd_s + nt * 16 + quad * 4);
    bd4[nt] = bt + bs;
  }

#pragma unroll 1
  for (int br = 0; br < 2; ++br) {
    const float* Wq = br ? Wq_s : Wq_t;
    const float* Wk = br ? Wk_s : Wk_t;
    const float* Wv = br ? Wv_s : Wv_t;
    const float* Wd = br ? Wd_s : Wd_t;

    // ---- stage W^T matrices into LDS (bf16) ----
    {
      const int d = tid >> 3;        // 0..63
      const int e0 = (tid & 7) * 8;  // 0..56
      const float* srcs[3] = {Wq, Wk, Wv};
#pragma unroll
      for (int g = 0; g < 3; ++g) {
        const float4v u = *reinterpret_cast<const float4v*>(srcs[g] + d * 64 + e0);
        const float4v v = *reinterpret_cast<const float4v*>(srcs[g] + d * 64 + e0 + 4);
        unsigned short* dst = Wst + g * 4096;
#pragma unroll
        for (int i = 0; i < 4; ++i) dst[wsw_idx(e0 + i, d)] = f2bf(u[i]);
#pragma unroll
        for (int i = 0; i < 4; ++i) dst[wsw_idx(e0 + 4 + i, d)] = f2bf(v[i]);
      }
      const float4v u = *reinterpret_cast<const float4v*>(Wd + d * 64 + e0);
      const float4v v = *reinterpret_cast<const float4v*>(Wd + d * 64 + e0 + 4);
#pragma unroll
      for (int i = 0; i < 4; ++i) Wdsw[wdsw_idx(e0 + i, d)] = f2bf(u[i]);
#pragma unroll
      for (int i = 0; i < 4; ++i) Wdsw[wdsw_idx(e0 + 4 + i, d)] = f2bf(v[i]);
    }
    __syncthreads();

    // ---- phase 1: Q^T,K^T,V^T = W^T @ X^T. Q -> global ws; K,V -> LDS ----
    // No hoisted W fragments, no cross-phase register state: keep the live set
    // round-0-small so s[32]/o[4] can own the accumulator file in phase 2.
#pragma unroll 1
    for (int mi = 0; mi < 4; ++mi) {
      const int mrow = (wv + mi * 8) * 16 + ln;
      short8 xa0, xa1;  // X^T B-frags (native 8-run)
      {
        const float4v u0 = *reinterpret_cast<const float4v*>(xb + mrow * 64 + quad * 8);
        const float4v v0 = *reinterpret_cast<const float4v*>(xb + mrow * 64 + quad * 8 + 4);
        const float4v u1 = *reinterpret_cast<const float4v*>(xb + mrow * 64 + 32 + quad * 8);
        const float4v v1 = *reinterpret_cast<const float4v*>(xb + mrow * 64 + 32 + quad * 8 + 4);
#pragma unroll
        for (int i = 0; i < 4; ++i) {
          xa0[i] = (short)f2bf(u0[i]);
          xa0[4 + i] = (short)f2bf(v0[i]);
          xa1[i] = (short)f2bf(u1[i]);
          xa1[4 + i] = (short)f2bf(v1[i]);
        }
      }
#pragma unroll
      for (int g = 0; g < 3; ++g) {
        const unsigned short* Wg = Wst + g * 4096;
#pragma unroll
        for (int nt = 0; nt < 4; ++nt) {
          const short8 w0 = *reinterpret_cast<const short8*>(Wg + wsw_idx(nt * 16 + ln, quad * 8));
          const short8 w1 = *reinterpret_cast<const short8*>(Wg + wsw_idx(nt * 16 + ln, 32 + quad * 8));
          float4v acc = {0.f, 0.f, 0.f, 0.f};
          acc = MFMA16(w0, xa0, acc);
          acc = MFMA16(w1, xa1, acc);
          // D-frag: acc[r] = M[mrow][e = nt*16 + quad*4 + r]
          if (g == 0) {
            short4v pk;
#pragma unroll
            for (int r = 0; r < 4; ++r) pk[r] = (short)f2bf(acc[r]);
            *reinterpret_cast<short4v*>(qg + mrow * 64 + nt * 16 + quad * 4) = pk;
          } else if (g == 1) {
            short4v pk;
#pragma unroll
            for (int r = 0; r < 4; ++r) pk[r] = (short)f2bf(acc[r]);
            *reinterpret_cast<short4v*>(Ksw + ksw_idx(mrow, nt * 16 + quad * 4)) = pk;
          } else {
#pragma unroll
            for (int r = 0; r < 4; ++r)
              Vsw[vsw_idx(mrow, nt * 16 + quad * 4 + r)] = f2bf(acc[r]);
          }
        }
      }
    }
    __syncthreads();

    // ---- phase 2: per wave q-tiles: S^T -> softmax (per-lane rows) -> O^T -> Z^T ----
#pragma unroll 1
    for (int qi = 0; qi < 4; ++qi) {
      const int qt = wv + qi * 8;
      // Q^T B-frags from workspace (split-4 slot bijection: j<4 -> d=cp*32+quad*4+j,
      // j>=4 -> d=cp*32+16+quad*4+(j-4)); lane's q = qt*16 + ln
      const unsigned short* qrow = qg + (qt * 16 + ln) * 64;
      const short8 qa = cat4(*reinterpret_cast<const short4v*>(qrow + quad * 4),
                             *reinterpret_cast<const short4v*>(qrow + 16 + quad * 4));
      const short8 qb = cat4(*reinterpret_cast<const short4v*>(qrow + 32 + quad * 4),
                             *reinterpret_cast<const short4v*>(qrow + 48 + quad * 4));

      // S^T = K @ Q^T: s[kt][r] at pos = kt*16 + quad*4 + r, q = qt*16 + ln
      float4v s[32];
#pragma unroll
      for (int kt = 0; kt < 32; ++kt) {
        float4v acc = {0.f, 0.f, 0.f, 0.f};
        {
          const short4v klo = *reinterpret_cast<const short4v*>(
              Ksw + ksw_idx(kt * 16 + ln, quad * 4));
          const short4v khi = *reinterpret_cast<const short4v*>(
              Ksw + ksw_idx(kt * 16 + ln, 16 + quad * 4));
          acc = MFMA16(cat4(klo, khi), qa, acc);
        }
        {
          const short4v klo = *reinterpret_cast<const short4v*>(
              Ksw + ksw_idx(kt * 16 + ln, 32 + quad * 4));
          const short4v khi = *reinterpret_cast<const short4v*>(
              Ksw + ksw_idx(kt * 16 + ln, 48 + quad * 4));
          acc = MFMA16(cat4(klo, khi), qb, acc);
        }
        s[kt] = acc;
      }

      // row max (q = ln fixed per lane)
      float4v m4 = s[0];
#pragma unroll
      for (int kt = 1; kt < 32; ++kt)
#pragma unroll
        for (int r = 0; r < 4; ++r) m4[r] = fmaxf(m4[r], s[kt][r]);
      float mx = fmaxf(fmaxf(m4[0], m4[1]), fmaxf(m4[2], m4[3]));
      mx = fmaxf(mx, __shfl_xor(mx, 16, 64));
      mx = fmaxf(mx, __shfl_xor(mx, 32, 64));
      const float offs = -mx * 0.125f;

      float sacc0 = 0.f, sacc1 = 0.f, sacc2 = 0.f, sacc3 = 0.f;
      float4v o[4];
#pragma unroll
      for (int i = 0; i < 4; ++i) o[i] = (float4v){0.f, 0.f, 0.f, 0.f};

      // P stays in registers; PV in 16 chunks of 32 positions
#pragma unroll
      for (int kp = 0; kp < 16; ++kp) {
        float p[8];
#pragma unroll
        for (int h = 0; h < 2; ++h) {
          const int kt = kp * 2 + h;
#pragma unroll
          for (int r = 0; r < 4; ++r)
            p[h * 4 + r] = __expf(fmaf(s[kt][r], 0.125f, offs));
        }
        sacc0 += p[0] + p[4]; sacc1 += p[1] + p[5];
        sacc2 += p[2] + p[6]; sacc3 += p[3] + p[7];
        short8 pf;
#pragma unroll
        for (int j = 0; j < 8; ++j) pf[j] = (short)f2bf(p[j]);
#pragma unroll
        for (int nto = 0; nto < 4; ++nto) {
          const short4v vlo = *reinterpret_cast<const short4v*>(
              Vsw + vsw_idx(kp * 32 + quad * 4, nto * 16 + ln));
          const short4v vhi = *reinterpret_cast<const short4v*>(
              Vsw + vsw_idx(kp * 32 + 16 + quad * 4, nto * 16 + ln));
          o[nto] = MFMA16(cat4(vlo, vhi), pf, o[nto]);  // O^T[d=nto*16+quad*4+r][q=ln]
        }
      }
      float sum = (sacc0 + sacc1) + (sacc2 + sacc3);
      sum += __shfl_xor(sum, 16, 64);
      sum += __shfl_xor(sum, 32, 64);
      const float inv = 1.0f / sum;

      // O^T -> bf16 B-frags (in-register)
      short8 of0, of1;
#pragma unroll
      for (int r = 0; r < 4; ++r) {
        of0[r] = (short)f2bf(o[0][r] * inv);
        of0[4 + r] = (short)f2bf(o[1][r] * inv);
        of1[r] = (short)f2bf(o[2][r] * inv);
        of1[4 + r] = (short)f2bf(o[3][r] * inv);
      }

      // dense: Z^T = Wd^T @ O^T; float4 epilogue
#pragma unroll
      for (int nt = 0; nt < 4; ++nt) {
        float4v acc = {0.f, 0.f, 0.f, 0.f};
        {
          const short4v wlo = *reinterpret_cast<const short4v*>(
              Wdsw + wdsw_idx(nt * 16 + ln, quad * 4));
          const short4v whi = *reinterpret_cast<const short4v*>(
              Wdsw + wdsw_idx(nt * 16 + ln, 16 + quad * 4));
          acc = MFMA16(cat4(wlo, whi), of0, acc);
        }
        {
          const short4v wlo = *reinterpret_cast<const short4v*>(
              Wdsw + wdsw_idx(nt * 16 + ln, 32 + quad * 4));
          const short4v whi = *reinterpret_cast<const short4v*>(
              Wdsw + wdsw_idx(nt * 16 + ln, 48 + quad * 4));
          acc = MFMA16(cat4(wlo, whi), of1, acc);
        }
        const int row = qt * 16 + ln;       // position
        const int e0 = nt * 16 + quad * 4;  // channel base (4 consecutive)
        float4v* op = reinterpret_cast<float4v*>(outb + row * 64 + e0);
        if (br == 0) {
          *op = acc;  // park temporal branch (sans bias)
        } else {
          const float4v parked = *op;
          const float4v xv = *reinterpret_cast<const float4v*>(xb + row * 64 + e0);
          float4v res;
#pragma unroll
          for (int r = 0; r < 4; ++r) {
            const float z = parked[r] + acc[r] + bd4[nt][r];
            const float gate = 1.0f / (1.0f + __expf(-z));
            res[r] = xv[r] * gate;
          }
          *op = res;
        }
      }
    }
    __syncthreads();  // protect K/V/W LDS before next branch restages
  }
}

extern "C" void kernel_launch(void* const* d_in, const int* in_sizes, int n_in,
                              void* d_out, int out_size, void* d_ws, size_t ws_size,
                              hipStream_t stream) {
  const float* x = (const float*)d_in[0];
  const float* Wq_t = (const float*)d_in[1];
  const float* Wk_t = (const float*)d_in[2];
  const float* Wv_t = (const float*)d_in[3];
  const float* Wq_s = (const float*)d_in[4];
  const float* Wk_s = (const float*)d_in[5];
  const float* Wv_s = (const float*)d_in[6];
  const float* Wd_t = (const float*)d_in[7];
  const float* bd_t = (const float*)d_in[8];
  const float* Wd_s = (const float*)d_in[9];
  const float* bd_s = (const float*)d_in[10];
  float* out = (float*)d_out;
  unsigned short* qws = (unsigned short*)d_ws;  // 256*512*64*2 = 16 MiB

  hipFuncSetAttribute(reinterpret_cast<const void*>(ts_attn_fused),
                      hipFuncAttributeMaxDynamicSharedMemorySize, LDS_TOTAL_BYTES);
  ts_attn_fused<<<dim3(256), dim3(kThreads), LDS_TOTAL_BYTES, stream>>>(
      x, Wq_t, Wk_t, Wv_t, Wq_s, Wk_s, Wv_s, Wd_t, bd_t, Wd_s, bd_s, out, qws);
}

// Round 5
// 736.386 us; speedup vs baseline: 1.2931x; 1.2931x over previous
//
#include <hip/hip_runtime.h>

typedef __attribute__((ext_vector_type(8))) short short8;
typedef __attribute__((ext_vector_type(4))) short short4v;
typedef __attribute__((ext_vector_type(4))) float float4v;

#define MFMA16(a, b, c) __builtin_amdgcn_mfma_f32_16x16x32_bf16((a), (b), (c), 0, 0, 0)

constexpr int kThreads = 512;
// LDS (ushort units):
//   [0,     32768)  K2 : pos-major; 8 granules of 16B per pos-row.
//                   granule g = cp*4+quad (XOR pos&7); content
//                   [K[pos][cp*32+quad*4+0..3], K[pos][cp*32+16+quad*4+0..3]]
//   [32768, 65536)  V2 : d-major; granule [quad][kp] (kp XOR d&7); content
//                   [V[kp*32+quad*4+0..3][d], V[kp*32+16+quad*4+0..3][d]]
//   [65536, 77824)  Wq^T/Wk^T/Wv^T staging (3 x 4096), 8-consecutive-d b128 frags
//   [77824, 81920)  Wd2 : e-major; granule g = cp*4+quad (XOR e&7); content
//                   [Wd[cp*32+quad*4+0..3][e], Wd[cp*32+16+quad*4+0..3][e]]
constexpr int LDS_TOTAL_BYTES = 163840;  // 160 KiB -> 1 block/CU

static __device__ __forceinline__ unsigned short f2bf(float f) {
  // round-to-nearest-even fp32 -> bf16
  unsigned int u = __float_as_uint(f);
  u = (u + 0x7fffu + ((u >> 16) & 1u)) >> 16;
  return (unsigned short)u;
}

// W^T staging swizzle for phase 1 (b128 frags of 8 consecutive d) — unchanged
// from the passing r4 kernel.
static __device__ __forceinline__ int wsw_idx(int e, int d) {
  return ((((d >> 3) << 9) + (e << 3) + (d & 7)) ^ (((d >> 3) & 3) << 3));
}

__global__ __launch_bounds__(kThreads, 2) void ts_attn_fused(
    const float* __restrict__ x, const float* __restrict__ Wq_t,
    const float* __restrict__ Wk_t, const float* __restrict__ Wv_t,
    const float* __restrict__ Wq_s, const float* __restrict__ Wk_s,
    const float* __restrict__ Wv_s, const float* __restrict__ Wd_t,
    const float* __restrict__ bd_t, const float* __restrict__ Wd_s,
    const float* __restrict__ bd_s, float* __restrict__ out,
    unsigned short* __restrict__ qws) {
  extern __shared__ __align__(16) unsigned short smem[];
  unsigned short* Ksw = smem;            // 32768 us
  unsigned short* Vsw = smem + 32768;    // 32768 us
  unsigned short* Wst = smem + 65536;    // 12288 us (3 x 4096)
  unsigned short* Wdsw = smem + 77824;   // 4096 us

  const int tid = threadIdx.x;
  const int wv = tid >> 6;
  const int lane = tid & 63;
  const int ln = lane & 15;   // q position within 16-tile
  const int quad = lane >> 4;
  const int e8 = ln & 7;      // lane-constant XOR key (pos&7 / e&7 of this lane's rows)
  const int b = blockIdx.x;

  const float* xb = x + (size_t)b * (512 * 64);
  float* outb = out + (size_t)b * (512 * 64);
  unsigned short* qg = qws + (size_t)b * (512 * 64);  // Q bf16 in slot-group order

  // bias preload: epilogue lane covers channels e = nt*16 + quad*4 + r
  float4v bd4[4];
#pragma unroll
  for (int nt = 0; nt < 4; ++nt) {
    const float4v bt = *reinterpret_cast<const float4v*>(bd_t + nt * 16 + quad * 4);
    const float4v bs = *reinterpret_cast<const float4v*>(bd_s + nt * 16 + quad * 4);
    bd4[nt] = bt + bs;
  }

#pragma unroll 1
  for (int br = 0; br < 2; ++br) {
    const float* Wq = br ? Wq_s : Wq_t;
    const float* Wk = br ? Wk_s : Wk_t;
    const float* Wv = br ? Wv_s : Wv_t;
    const float* Wd = br ? Wd_s : Wd_t;

    // ---- stage weight matrices into LDS (bf16) ----
    {
      const int d = tid >> 3;        // 0..63
      const int e0 = (tid & 7) * 8;  // 0..56
      const float* srcs[3] = {Wq, Wk, Wv};
#pragma unroll
      for (int g = 0; g < 3; ++g) {
        const float4v u = *reinterpret_cast<const float4v*>(srcs[g] + d * 64 + e0);
        const float4v v = *reinterpret_cast<const float4v*>(srcs[g] + d * 64 + e0 + 4);
        unsigned short* dst = Wst + g * 4096;
#pragma unroll
        for (int i = 0; i < 4; ++i) dst[wsw_idx(e0 + i, d)] = f2bf(u[i]);
#pragma unroll
        for (int i = 0; i < 4; ++i) dst[wsw_idx(e0 + 4 + i, d)] = f2bf(v[i]);
      }
      // Wd -> Wd2 slot-group layout: d -> (cp, quad_g, h)
      const int cp_ = d >> 5;
      const int c = d & 31;
      const int qd_ = (c >> 2) & 3;
      const int h_ = ((c >> 4) << 2) | (c & 3);
      const int gbase = (cp_ * 4 + qd_);
      const float4v u = *reinterpret_cast<const float4v*>(Wd + d * 64 + e0);
      const float4v v = *reinterpret_cast<const float4v*>(Wd + d * 64 + e0 + 4);
#pragma unroll
      for (int i = 0; i < 4; ++i) {
        const int e = e0 + i;
        Wdsw[e * 64 + ((gbase ^ (e & 7)) << 3) + h_] = f2bf(u[i]);
      }
#pragma unroll
      for (int i = 0; i < 4; ++i) {
        const int e = e0 + 4 + i;
        Wdsw[e * 64 + ((gbase ^ (e & 7)) << 3) + h_] = f2bf(v[i]);
      }
    }
    __syncthreads();

    // ---- phase 1: Q^T,K^T,V^T = W^T @ X^T. Q -> global ws; K,V -> LDS ----
#pragma unroll 1
    for (int mi = 0; mi < 4; ++mi) {
      const int mrow = (wv + mi * 8) * 16 + ln;
      // V2 decomposition of this row's position (for g==2 writes)
      const int kpq = mrow >> 5;
      const int w5 = mrow & 31;
      const int jj = ((w5 >> 4) << 2) | (w5 & 3);
      const int qg2 = (w5 >> 2) & 3;
      short8 xa0, xa1;  // X^T B-frags (native 8-run: slot j -> d = cc*32 + quad*8 + j)
      {
        const float4v u0 = *reinterpret_cast<const float4v*>(xb + mrow * 64 + quad * 8);
        const float4v v0 = *reinterpret_cast<const float4v*>(xb + mrow * 64 + quad * 8 + 4);
        const float4v u1 = *reinterpret_cast<const float4v*>(xb + mrow * 64 + 32 + quad * 8);
        const float4v v1 = *reinterpret_cast<const float4v*>(xb + mrow * 64 + 32 + quad * 8 + 4);
#pragma unroll
        for (int i = 0; i < 4; ++i) {
          xa0[i] = (short)f2bf(u0[i]);
          xa0[4 + i] = (short)f2bf(v0[i]);
          xa1[i] = (short)f2bf(u1[i]);
          xa1[4 + i] = (short)f2bf(v1[i]);
        }
      }
#pragma unroll
      for (int g = 0; g < 3; ++g) {
        const unsigned short* Wg = Wst + g * 4096;
#pragma unroll
        for (int nt = 0; nt < 4; ++nt) {
          const short8 w0 = *reinterpret_cast<const short8*>(Wg + wsw_idx(nt * 16 + ln, quad * 8));
          const short8 w1 = *reinterpret_cast<const short8*>(Wg + wsw_idx(nt * 16 + ln, 32 + quad * 8));
          float4v acc = {0.f, 0.f, 0.f, 0.f};
          acc = MFMA16(w0, xa0, acc);
          acc = MFMA16(w1, xa1, acc);
          // D-frag: acc[r] = M[mrow][e = nt*16 + quad*4 + r]
          // slot-group coords: cp = nt>>1, h = (nt&1)*4 + r, granule quad-field = quad
          if (g == 0) {
            short4v pk;
#pragma unroll
            for (int r = 0; r < 4; ++r) pk[r] = (short)f2bf(acc[r]);
            *reinterpret_cast<short4v*>(
                qg + mrow * 64 + (nt >> 1) * 32 + quad * 8 + (nt & 1) * 4) = pk;
          } else if (g == 1) {
            short4v pk;
#pragma unroll
            for (int r = 0; r < 4; ++r) pk[r] = (short)f2bf(acc[r]);
            const int gswz = ((nt >> 1) * 4 + quad) ^ (mrow & 7);
            *reinterpret_cast<short4v*>(
                Ksw + mrow * 64 + (gswz << 3) + (nt & 1) * 4) = pk;
          } else {
#pragma unroll
            for (int r = 0; r < 4; ++r) {
              const int d = nt * 16 + quad * 4 + r;
              Vsw[(d << 9) + (qg2 << 7) + ((kpq ^ (d & 7)) << 3) + jj] = f2bf(acc[r]);
            }
          }
        }
      }
    }
    __syncthreads();

    // ---- phase 2: per wave q-tiles: S^T -> softmax (per-lane rows) -> O^T -> Z^T ----
    // All operands are single b128 loads in slot-group order (no concat ops).
#pragma unroll 1
    for (int qi = 0; qi < 4; ++qi) {
      const int qt = wv + qi * 8;
      // Q^T B-frags: slot j -> d = cp*32 + (j>>2)*16 + quad*4 + (j&3); q = qt*16+ln
      const unsigned short* qrow = qg + (qt * 16 + ln) * 64;
      const short8 qa = *reinterpret_cast<const short8*>(qrow + quad * 8);
      const short8 qb = *reinterpret_cast<const short8*>(qrow + 32 + quad * 8);

      // S^T = K @ Q^T: s[kt][r] at pos = kt*16 + quad*4 + r, q = qt*16 + ln
      const int kb0 = ln * 64 + ((quad ^ e8) << 3);        // cp=0 granule
      const int kb1 = ln * 64 + (((4 + quad) ^ e8) << 3);  // cp=1 granule
      float4v s[32];
#pragma unroll
      for (int kt = 0; kt < 32; ++kt) {
        const short8 k0 = *reinterpret_cast<const short8*>(Ksw + kt * 1024 + kb0);
        const short8 k1 = *reinterpret_cast<const short8*>(Ksw + kt * 1024 + kb1);
        float4v acc = {0.f, 0.f, 0.f, 0.f};
        acc = MFMA16(k0, qa, acc);
        acc = MFMA16(k1, qb, acc);
        s[kt] = acc;
      }

      // row max (q = ln fixed per lane)
      float4v m4 = s[0];
#pragma unroll
      for (int kt = 1; kt < 32; ++kt)
#pragma unroll
        for (int r = 0; r < 4; ++r) m4[r] = fmaxf(m4[r], s[kt][r]);
      float mx = fmaxf(fmaxf(m4[0], m4[1]), fmaxf(m4[2], m4[3]));
      mx = fmaxf(mx, __shfl_xor(mx, 16, 64));
      mx = fmaxf(mx, __shfl_xor(mx, 32, 64));
      const float offs = -mx * 0.125f;

      float sacc0 = 0.f, sacc1 = 0.f, sacc2 = 0.f, sacc3 = 0.f;
      float4v o[4];
#pragma unroll
      for (int i = 0; i < 4; ++i) o[i] = (float4v){0.f, 0.f, 0.f, 0.f};

      // P stays in registers; PV in 16 chunks of 32 positions
      const int e88 = e8 * 8;
#pragma unroll
      for (int kp = 0; kp < 16; ++kp) {
        float p[8];
#pragma unroll
        for (int h = 0; h < 2; ++h) {
          const int kt = kp * 2 + h;
#pragma unroll
          for (int r = 0; r < 4; ++r)
            p[h * 4 + r] = __expf(fmaf(s[kt][r], 0.125f, offs));
        }
        sacc0 += p[0] + p[4]; sacc1 += p[1] + p[5];
        sacc2 += p[2] + p[6]; sacc3 += p[3] + p[7];
        // P^T B-frag: slot j -> pos = kp*32 + (j>>2)*16 + quad*4 + (j&3)
        short8 pf;
#pragma unroll
        for (int j = 0; j < 8; ++j) pf[j] = (short)f2bf(p[j]);
#pragma unroll
        for (int nto = 0; nto < 4; ++nto) {
          // V A-frag: same slot->pos bijection, channel d = nto*16 + ln
          const int vb = (nto * 16 + ln) * 512 + quad * 128;
          const short8 vf = *reinterpret_cast<const short8*>(Vsw + vb + ((kp * 8) ^ e88));
          o[nto] = MFMA16(vf, pf, o[nto]);  // O^T[d = nto*16+quad*4+r][q = ln]
        }
      }
      float sum = (sacc0 + sacc1) + (sacc2 + sacc3);
      sum += __shfl_xor(sum, 16, 64);
      sum += __shfl_xor(sum, 32, 64);
      const float inv = 1.0f / sum;

      // O^T -> bf16 B-frags: of0 slot j -> d = (j>>2)*16 + quad*4 + (j&3); of1: +32
      short8 of0, of1;
#pragma unroll
      for (int r = 0; r < 4; ++r) {
        of0[r] = (short)f2bf(o[0][r] * inv);
        of0[4 + r] = (short)f2bf(o[1][r] * inv);
        of1[r] = (short)f2bf(o[2][r] * inv);
        of1[4 + r] = (short)f2bf(o[3][r] * inv);
      }

      // dense: Z^T = Wd^T @ O^T; float4 epilogue
#pragma unroll
      for (int nt = 0; nt < 4; ++nt) {
        const int ebase = (nt * 16 + ln) * 64;
        const short8 w0 = *reinterpret_cast<const short8*>(
            Wdsw + ebase + ((quad ^ e8) << 3));
        const short8 w1 = *reinterpret_cast<const short8*>(
            Wdsw + ebase + (((4 + quad) ^ e8) << 3));
        float4v acc = {0.f, 0.f, 0.f, 0.f};
        acc = MFMA16(w0, of0, acc);
        acc = MFMA16(w1, of1, acc);
        const int row = qt * 16 + ln;       // position
        const int e0 = nt * 16 + quad * 4;  // channel base (4 consecutive)
        float4v* op = reinterpret_cast<float4v*>(outb + row * 64 + e0);
        if (br == 0) {
          *op = acc;  // park temporal branch (sans bias)
        } else {
          const float4v parked = *op;
          const float4v xv = *reinterpret_cast<const float4v*>(xb + row * 64 + e0);
          float4v res;
#pragma unroll
          for (int r = 0; r < 4; ++r) {
            const float z = parked[r] + acc[r] + bd4[nt][r];
            const float gate = 1.0f / (1.0f + __expf(-z));
            res[r] = xv[r] * gate;
          }
          *op = res;
        }
      }
    }
    __syncthreads();  // protect K/V/W LDS before next branch restages
  }
}

extern "C" void kernel_launch(void* const* d_in, const int* in_sizes, int n_in,
                              void* d_out, int out_size, void* d_ws, size_t ws_size,
                              hipStream_t stream) {
  const float* x = (const float*)d_in[0];
  const float* Wq_t = (const float*)d_in[1];
  const float* Wk_t = (const float*)d_in[2];
  const float* Wv_t = (const float*)d_in[3];
  const float* Wq_s = (const float*)d_in[4];
  const float* Wk_s = (const float*)d_in[5];
  const float* Wv_s = (const float*)d_in[6];
  const float* Wd_t = (const float*)d_in[7];
  const float* bd_t = (const float*)d_in[8];
  const float* Wd_s = (const float*)d_in[9];
  const float* bd_s = (const float*)d_in[10];
  float* out = (float*)d_out;
  unsigned short* qws = (unsigned short*)d_ws;  // 256*512*64*2 = 16 MiB

  hipFuncSetAttribute(reinterpret_cast<const void*>(ts_attn_fused),
                      hipFuncAttributeMaxDynamicSharedMemorySize, LDS_TOTAL_BYTES);
  ts_attn_fused<<<dim3(256), dim3(kThreads), LDS_TOTAL_BYTES, stream>>>(
      x, Wq_t, Wk_t, Wv_t, Wq_s, Wk_s, Wv_s, Wd_t, bd_t, Wd_s, bd_s, out, qws);
}

// Round 6
// 180.528 us; speedup vs baseline: 5.2745x; 4.0791x over previous
//
#include <hip/hip_runtime.h>

typedef __attribute__((ext_vector_type(8))) short short8;
typedef __attribute__((ext_vector_type(4))) short short4v;
typedef __attribute__((ext_vector_type(4))) float float4v;

#define MFMA16(a, b, c) __builtin_amdgcn_mfma_f32_16x16x32_bf16((a), (b), (c), 0, 0, 0)

constexpr int kThreads = 512;
// LDS (ushort units):
//   [0,     32768)  K2 : pos-major; 8 granules of 16B per pos-row.
//                   granule g = cp*4+quad (XOR pos&7); content
//                   [K[pos][cp*32+quad*4+0..3], K[pos][cp*32+16+quad*4+0..3]]
//   [32768, 65536)  V2 : d-major; granule [quad][kp] (kp XOR d&7); content
//                   [V[kp*32+quad*4+0..3][d], V[kp*32+16+quad*4+0..3][d]]
//   [65536, 77824)  Wq^T/Wk^T/Wv^T staging (3 x 4096), 8-consecutive-d b128 frags
//   [77824, 81920)  Wd2 : e-major; granule g = cp*4+quad (XOR e&7); content
//                   [Wd[cp*32+quad*4+0..3][e], Wd[cp*32+16+quad*4+0..3][e]]
constexpr int LDS_TOTAL_BYTES = 163840;  // 160 KiB -> 1 block/CU
// NOTE: 1 block/CU => all 8 waves resident at 2/SIMD => hard budget of 256
// unified VGPR+AGPR per wave. Keep peak liveness well under it (the s[32]
// full-S variant spilled ~12 KB/thread of scratch -> 1.7 GB HBM traffic).

static __device__ __forceinline__ unsigned short f2bf(float f) {
  // round-to-nearest-even fp32 -> bf16
  unsigned int u = __float_as_uint(f);
  u = (u + 0x7fffu + ((u >> 16) & 1u)) >> 16;
  return (unsigned short)u;
}

// W^T staging swizzle for phase 1 (b128 frags of 8 consecutive d).
static __device__ __forceinline__ int wsw_idx(int e, int d) {
  return ((((d >> 3) << 9) + (e << 3) + (d & 7)) ^ (((d >> 3) & 3) << 3));
}

__global__ __launch_bounds__(kThreads, 2) void ts_attn_fused(
    const float* __restrict__ x, const float* __restrict__ Wq_t,
    const float* __restrict__ Wk_t, const float* __restrict__ Wv_t,
    const float* __restrict__ Wq_s, const float* __restrict__ Wk_s,
    const float* __restrict__ Wv_s, const float* __restrict__ Wd_t,
    const float* __restrict__ bd_t, const float* __restrict__ Wd_s,
    const float* __restrict__ bd_s, float* __restrict__ out,
    unsigned short* __restrict__ qws) {
  extern __shared__ __align__(16) unsigned short smem[];
  unsigned short* Ksw = smem;            // 32768 us
  unsigned short* Vsw = smem + 32768;    // 32768 us
  unsigned short* Wst = smem + 65536;    // 12288 us (3 x 4096)
  unsigned short* Wdsw = smem + 77824;   // 4096 us

  const int tid = threadIdx.x;
  const int wv = tid >> 6;
  const int lane = tid & 63;
  const int ln = lane & 15;   // q position within 16-tile
  const int quad = lane >> 4;
  const int e8 = ln & 7;      // lane-constant XOR key (pos&7 / e&7 of this lane's rows)
  const int b = blockIdx.x;

  const float* xb = x + (size_t)b * (512 * 64);
  float* outb = out + (size_t)b * (512 * 64);
  unsigned short* qg = qws + (size_t)b * (512 * 64);  // Q bf16 in slot-group order

  // bias preload: epilogue lane covers channels e = nt*16 + quad*4 + r
  float4v bd4[4];
#pragma unroll
  for (int nt = 0; nt < 4; ++nt) {
    const float4v bt = *reinterpret_cast<const float4v*>(bd_t + nt * 16 + quad * 4);
    const float4v bs = *reinterpret_cast<const float4v*>(bd_s + nt * 16 + quad * 4);
    bd4[nt] = bt + bs;
  }

#pragma unroll 1
  for (int br = 0; br < 2; ++br) {
    const float* Wq = br ? Wq_s : Wq_t;
    const float* Wk = br ? Wk_s : Wk_t;
    const float* Wv = br ? Wv_s : Wv_t;
    const float* Wd = br ? Wd_s : Wd_t;

    // ---- stage weight matrices into LDS (bf16) ----
    {
      const int d = tid >> 3;        // 0..63
      const int e0 = (tid & 7) * 8;  // 0..56
      const float* srcs[3] = {Wq, Wk, Wv};
#pragma unroll
      for (int g = 0; g < 3; ++g) {
        const float4v u = *reinterpret_cast<const float4v*>(srcs[g] + d * 64 + e0);
        const float4v v = *reinterpret_cast<const float4v*>(srcs[g] + d * 64 + e0 + 4);
        unsigned short* dst = Wst + g * 4096;
#pragma unroll
        for (int i = 0; i < 4; ++i) dst[wsw_idx(e0 + i, d)] = f2bf(u[i]);
#pragma unroll
        for (int i = 0; i < 4; ++i) dst[wsw_idx(e0 + 4 + i, d)] = f2bf(v[i]);
      }
      // Wd -> Wd2 slot-group layout: d -> (cp, quad_g, h)
      const int cp_ = d >> 5;
      const int c = d & 31;
      const int qd_ = (c >> 2) & 3;
      const int h_ = ((c >> 4) << 2) | (c & 3);
      const int gbase = (cp_ * 4 + qd_);
      const float4v u = *reinterpret_cast<const float4v*>(Wd + d * 64 + e0);
      const float4v v = *reinterpret_cast<const float4v*>(Wd + d * 64 + e0 + 4);
#pragma unroll
      for (int i = 0; i < 4; ++i) {
        const int e = e0 + i;
        Wdsw[e * 64 + ((gbase ^ (e & 7)) << 3) + h_] = f2bf(u[i]);
      }
#pragma unroll
      for (int i = 0; i < 4; ++i) {
        const int e = e0 + 4 + i;
        Wdsw[e * 64 + ((gbase ^ (e & 7)) << 3) + h_] = f2bf(v[i]);
      }
    }
    __syncthreads();

    // ---- phase 1: Q^T,K^T,V^T = W^T @ X^T. Q -> global ws; K,V -> LDS ----
#pragma unroll 1
    for (int mi = 0; mi < 4; ++mi) {
      const int mrow = (wv + mi * 8) * 16 + ln;
      // V2 decomposition of this row's position (for g==2 writes)
      const int kpq = mrow >> 5;
      const int w5 = mrow & 31;
      const int jj = ((w5 >> 4) << 2) | (w5 & 3);
      const int qg2 = (w5 >> 2) & 3;
      short8 xa0, xa1;  // X^T B-frags (native 8-run: slot j -> d = cc*32 + quad*8 + j)
      {
        const float4v u0 = *reinterpret_cast<const float4v*>(xb + mrow * 64 + quad * 8);
        const float4v v0 = *reinterpret_cast<const float4v*>(xb + mrow * 64 + quad * 8 + 4);
        const float4v u1 = *reinterpret_cast<const float4v*>(xb + mrow * 64 + 32 + quad * 8);
        const float4v v1 = *reinterpret_cast<const float4v*>(xb + mrow * 64 + 32 + quad * 8 + 4);
#pragma unroll
        for (int i = 0; i < 4; ++i) {
          xa0[i] = (short)f2bf(u0[i]);
          xa0[4 + i] = (short)f2bf(v0[i]);
          xa1[i] = (short)f2bf(u1[i]);
          xa1[4 + i] = (short)f2bf(v1[i]);
        }
      }
#pragma unroll
      for (int g = 0; g < 3; ++g) {
        const unsigned short* Wg = Wst + g * 4096;
#pragma unroll
        for (int nt = 0; nt < 4; ++nt) {
          const short8 w0 = *reinterpret_cast<const short8*>(Wg + wsw_idx(nt * 16 + ln, quad * 8));
          const short8 w1 = *reinterpret_cast<const short8*>(Wg + wsw_idx(nt * 16 + ln, 32 + quad * 8));
          float4v acc = {0.f, 0.f, 0.f, 0.f};
          acc = MFMA16(w0, xa0, acc);
          acc = MFMA16(w1, xa1, acc);
          // D-frag: acc[r] = M[mrow][e = nt*16 + quad*4 + r]
          if (g == 0) {
            short4v pk;
#pragma unroll
            for (int r = 0; r < 4; ++r) pk[r] = (short)f2bf(acc[r]);
            *reinterpret_cast<short4v*>(
                qg + mrow * 64 + (nt >> 1) * 32 + quad * 8 + (nt & 1) * 4) = pk;
          } else if (g == 1) {
            short4v pk;
#pragma unroll
            for (int r = 0; r < 4; ++r) pk[r] = (short)f2bf(acc[r]);
            const int gswz = ((nt >> 1) * 4 + quad) ^ (mrow & 7);
            *reinterpret_cast<short4v*>(
                Ksw + mrow * 64 + (gswz << 3) + (nt & 1) * 4) = pk;
          } else {
#pragma unroll
            for (int r = 0; r < 4; ++r) {
              const int d = nt * 16 + quad * 4 + r;
              Vsw[(d << 9) + (qg2 << 7) + ((kpq ^ (d & 7)) << 3) + jj] = f2bf(acc[r]);
            }
          }
        }
      }
    }
    __syncthreads();

    // ---- phase 2: per wave q-tiles, ONLINE softmax over 4 chunks of 128 pos ----
#pragma unroll 1
    for (int qi = 0; qi < 4; ++qi) {
      const int qt = wv + qi * 8;
      // Q^T B-frags: slot j -> d = cp*32 + (j>>2)*16 + quad*4 + (j&3); q = qt*16+ln
      const unsigned short* qrow = qg + (qt * 16 + ln) * 64;
      const short8 qa = *reinterpret_cast<const short8*>(qrow + quad * 8);
      const short8 qb = *reinterpret_cast<const short8*>(qrow + 32 + quad * 8);

      const int kb0 = ln * 64 + ((quad ^ e8) << 3);        // cp=0 granule
      const int kb1 = ln * 64 + (((4 + quad) ^ e8) << 3);  // cp=1 granule
      const int e88 = e8 * 8;

      float4v o[4];
#pragma unroll
      for (int i = 0; i < 4; ++i) o[i] = (float4v){0.f, 0.f, 0.f, 0.f};
      float mrun = -3.0e38f;
      float sum = 0.f;

#pragma unroll 1
      for (int ch = 0; ch < 4; ++ch) {
        // S chunk: s[k8][r] at pos = (ch*8+k8)*16 + quad*4 + r, q = qt*16 + ln
        float4v s[8];
#pragma unroll
        for (int k8 = 0; k8 < 8; ++k8) {
          const int kt = ch * 8 + k8;
          const short8 k0 = *reinterpret_cast<const short8*>(Ksw + kt * 1024 + kb0);
          const short8 k1 = *reinterpret_cast<const short8*>(Ksw + kt * 1024 + kb1);
          float4v acc = {0.f, 0.f, 0.f, 0.f};
          acc = MFMA16(k0, qa, acc);
          acc = MFMA16(k1, qb, acc);
          s[k8] = acc;
        }

        // chunk max across this lane's 32 values, then across the 4 quads
        float4v m4 = s[0];
#pragma unroll
        for (int k8 = 1; k8 < 8; ++k8)
#pragma unroll
          for (int r = 0; r < 4; ++r) m4[r] = fmaxf(m4[r], s[k8][r]);
        float cmx = fmaxf(fmaxf(m4[0], m4[1]), fmaxf(m4[2], m4[3]));
        cmx = fmaxf(cmx, __shfl_xor(cmx, 16, 64));
        cmx = fmaxf(cmx, __shfl_xor(cmx, 32, 64));

        const float mnew = fmaxf(mrun, cmx);     // uniform across ln-group
        const float scale = __expf((mrun - mnew) * 0.125f);  // 0 on first chunk
        sum *= scale;
#pragma unroll
        for (int i = 0; i < 4; ++i)
#pragma unroll
          for (int r = 0; r < 4; ++r) o[i][r] *= scale;
        const float offs = -mnew * 0.125f;
        mrun = mnew;

        // exp -> pack -> PV (4 sub-chunks of 32 positions)
#pragma unroll
        for (int kp = 0; kp < 4; ++kp) {
          float p[8];
#pragma unroll
          for (int h = 0; h < 2; ++h) {
            const int k8 = kp * 2 + h;
#pragma unroll
            for (int r = 0; r < 4; ++r)
              p[h * 4 + r] = __expf(fmaf(s[k8][r], 0.125f, offs));
          }
          sum += ((p[0] + p[4]) + (p[1] + p[5])) + ((p[2] + p[6]) + (p[3] + p[7]));
          // P^T B-frag: slot j -> pos = kpg*32 + (j>>2)*16 + quad*4 + (j&3)
          short8 pf;
#pragma unroll
          for (int j = 0; j < 8; ++j) pf[j] = (short)f2bf(p[j]);
          const int kpg = ch * 4 + kp;
#pragma unroll
          for (int nto = 0; nto < 4; ++nto) {
            // V A-frag: same slot->pos bijection, channel d = nto*16 + ln
            const int vb = (nto * 16 + ln) * 512 + quad * 128;
            const short8 vf = *reinterpret_cast<const short8*>(Vsw + vb + ((kpg * 8) ^ e88));
            o[nto] = MFMA16(vf, pf, o[nto]);  // O^T[d = nto*16+quad*4+r][q = ln]
          }
        }
      }

      sum += __shfl_xor(sum, 16, 64);
      sum += __shfl_xor(sum, 32, 64);
      const float inv = 1.0f / sum;

      // O^T -> bf16 B-frags: of0 slot j -> d = (j>>2)*16 + quad*4 + (j&3); of1: +32
      short8 of0, of1;
#pragma unroll
      for (int r = 0; r < 4; ++r) {
        of0[r] = (short)f2bf(o[0][r] * inv);
        of0[4 + r] = (short)f2bf(o[1][r] * inv);
        of1[r] = (short)f2bf(o[2][r] * inv);
        of1[4 + r] = (short)f2bf(o[3][r] * inv);
      }

      // dense: Z^T = Wd^T @ O^T; float4 epilogue
#pragma unroll
      for (int nt = 0; nt < 4; ++nt) {
        const int ebase = (nt * 16 + ln) * 64;
        const short8 w0 = *reinterpret_cast<const short8*>(
            Wdsw + ebase + ((quad ^ e8) << 3));
        const short8 w1 = *reinterpret_cast<const short8*>(
            Wdsw + ebase + (((4 + quad) ^ e8) << 3));
        float4v acc = {0.f, 0.f, 0.f, 0.f};
        acc = MFMA16(w0, of0, acc);
        acc = MFMA16(w1, of1, acc);
        const int row = qt * 16 + ln;       // position
        const int e0 = nt * 16 + quad * 4;  // channel base (4 consecutive)
        float4v* op = reinterpret_cast<float4v*>(outb + row * 64 + e0);
        if (br == 0) {
          *op = acc;  // park temporal branch (sans bias)
        } else {
          const float4v parked = *op;
          const float4v xv = *reinterpret_cast<const float4v*>(xb + row * 64 + e0);
          float4v res;
#pragma unroll
          for (int r = 0; r < 4; ++r) {
            const float z = parked[r] + acc[r] + bd4[nt][r];
            const float gate = 1.0f / (1.0f + __expf(-z));
            res[r] = xv[r] * gate;
          }
          *op = res;
        }
      }
    }
    __syncthreads();  // protect K/V/W LDS before next branch restages
  }
}

extern "C" void kernel_launch(void* const* d_in, const int* in_sizes, int n_in,
                              void* d_out, int out_size, void* d_ws, size_t ws_size,
                              hipStream_t stream) {
  const float* x = (const float*)d_in[0];
  const float* Wq_t = (const float*)d_in[1];
  const float* Wk_t = (const float*)d_in[2];
  const float* Wv_t = (const float*)d_in[3];
  const float* Wq_s = (const float*)d_in[4];
  const float* Wk_s = (const float*)d_in[5];
  const float* Wv_s = (const float*)d_in[6];
  const float* Wd_t = (const float*)d_in[7];
  const float* bd_t = (const float*)d_in[8];
  const float* Wd_s = (const float*)d_in[9];
  const float* bd_s = (const float*)d_in[10];
  float* out = (float*)d_out;
  unsigned short* qws = (unsigned short*)d_ws;  // 256*512*64*2 = 16 MiB

  hipFuncSetAttribute(reinterpret_cast<const void*>(ts_attn_fused),
                      hipFuncAttributeMaxDynamicSharedMemorySize, LDS_TOTAL_BYTES);
  ts_attn_fused<<<dim3(256), dim3(kThreads), LDS_TOTAL_BYTES, stream>>>(
      x, Wq_t, Wk_t, Wv_t, Wq_s, Wk_s, Wv_s, Wd_t, bd_t, Wd_s, bd_s, out, qws);
}